// Round 11
// baseline (185.770 us; speedup 1.0000x reference)
//
#include <hip/hip_runtime.h>
#include <hip/hip_bf16.h>

#define OUT_SCALE 0.030197383422318501f  // exp(-3.5)

typedef __attribute__((ext_vector_type(8))) short bf16x8;
typedef __attribute__((ext_vector_type(4))) float f32x4;

#define EL_BLOCKS 2048
#define NUC_BLOCKS 2048

__device__ __forceinline__ unsigned pk2(float a, float b) {
  __hip_bfloat162 h = __float22bfloat162_rn(make_float2(a, b));
  unsigned u;
  __builtin_memcpy(&u, &h, 4);
  return u;
}

__device__ __forceinline__ float silu_f(float h) {
  return h * __builtin_amdgcn_rcpf(1.0f + __expf(-h));
}

// ---------------------------------------------------------------------------
// Prep: pack w1_el / w1_nuc into MFMA fragment layout, bf16.
// Fragment (mlp, kk, kg, col) = 8 bf16 of w1[kk*32+kg*8 .. +8)[col].
// ---------------------------------------------------------------------------
__global__ void prep_w1(const float* __restrict__ w1a,
                        const float* __restrict__ w1b,
                        unsigned short* __restrict__ wp) {
  int gid = blockIdx.x * 256 + threadIdx.x;  // 16384 fragments
  const float* w1 = (gid < 8192) ? w1a : w1b;
  int rem = gid & 8191;
  int kk = rem >> 10;
  int kg = (rem >> 8) & 3;
  int col = rem & 255;
  const float* src = w1 + (kk * 32 + kg * 8) * 256 + col;
  uint4 v;
  v.x = pk2(src[0 * 256], src[1 * 256]);
  v.y = pk2(src[2 * 256], src[3 * 256]);
  v.z = pk2(src[4 * 256], src[5 * 256]);
  v.w = pk2(src[6 * 256], src[7 * 256]);
  *(uint4*)(wp + (size_t)gid * 8) = v;
}

// ---------------------------------------------------------------------------
// Fused main kernel, 512 threads = 8 waves x 32 hidden-cols, 8 pairs/block.
// nt-PHASE SPLIT: per chunk, the wave's two 16-col groups are processed as
// two sequential phases, each holding only FOUR W1 fragments (16 VGPR)
// reloaded from the L1-resident packed buffer. This cuts arch-VGPR below
// the (512,6) budget (~42 under the split-file model deduced from r8-r10:
// occupancy = w/8, archVGPR budget = (512/w)/2) -> 63% occupancy, NO spill.
// ---------------------------------------------------------------------------
__global__ __launch_bounds__(512, 6) void bf_main_kernel(
    const float* __restrict__ rs, const float* __restrict__ msg_el,
    const float* __restrict__ msg_nuc, const float* __restrict__ emb,
    const unsigned short* __restrict__ wpk,
    const float* __restrict__ b1_el, const float* __restrict__ w2_el,
    const float* __restrict__ b2_el,
    const float* __restrict__ b1_nuc, const float* __restrict__ w2_nuc,
    const float* __restrict__ b2_nuc,
    const float* __restrict__ coords, const float* __restrict__ chg,
    float* __restrict__ out) {
  __shared__ __align__(16) unsigned short s_emb[16 * 128];      // 4 KB
  __shared__ __align__(16) unsigned short s_msg[2 * 32 * 128];  // 16 KB
  __shared__ __align__(16) float s_embc[8 * 256];               // 8 KB
  __shared__ __align__(16) float s_w2[256];                     // 1 KB
  __shared__ float s_fp[8][256];                                // 8 KB
  __shared__ float s_ps[8][4];
  __shared__ float s_decay[8];

  const int tid = threadIdx.x;
  const int bid = blockIdx.x;
  const int lane = tid & 63;
  const int wv = tid >> 6;
  const int cIdx = lane & 15, kg = lane >> 4;
  const int lr = tid >> 4, ch2 = tid & 15;  // staging row / chunk

  if (bid < EL_BLOCKS) {
    // ======================= EL PATH =======================
    const int gp0 = bid * 8;
    const float* msg = msg_el;

    if (tid < 32) ((float*)s_ps)[tid] = 0.0f;

    // ---- stage emb (8 pairs, swizzled; zero rows 8..15) ----
    {
      int p = tid >> 4, ch = tid & 15;
      if (tid < 128) {
        const float* src = emb + (gp0 + p) * 128 + ch * 8;
        float4 v0 = *(const float4*)src;
        float4 v1 = *(const float4*)(src + 4);
        uint4 pk;
        pk.x = pk2(v0.x, v0.y); pk.y = pk2(v0.z, v0.w);
        pk.z = pk2(v1.x, v1.y); pk.w = pk2(v1.z, v1.w);
        *(uint4*)(s_emb + p * 128 + (ch ^ p) * 8) = pk;
      } else if (tid < 256) {
        uint4 z = {0u, 0u, 0u, 0u};
        *(uint4*)(s_emb + p * 128 + (ch ^ (p & 15)) * 8) = z;
      }
      if (tid < 256) s_w2[tid] = w2_el[tid];
    }

    const int col = wv * 32 + cIdx;

    // ---- issue chunk-0 loads (chunk == pair; j = lr, clamp 31->30) ----
    const int jc = (lr < 31) ? lr : 30;
    const float* mptr = msg + (size_t)(gp0 * 31 + jc) * 128 + ch2 * 8;
    float4 la = *(const float4*)mptr;
    float4 lb = *(const float4*)(mptr + 4);
    mptr += 31 * 128;

    __syncthreads();

    // ---- phase 1: emb contribution per pair, nt-split, +b1 at store ----
    {
      bf16x8 Bq[4];
#pragma unroll
      for (int kk = 0; kk < 4; ++kk)
        Bq[kk] = *(const bf16x8*)(wpk + (size_t)((kk * 4 + kg) * 256 + col) * 8);
      f32x4 aE = {0, 0, 0, 0};
#pragma unroll
      for (int kk = 0; kk < 4; ++kk) {
        bf16x8 a = *(const bf16x8*)(s_emb + cIdx * 128 + ((kk * 4 + kg) ^ cIdx) * 8);
        aE = __builtin_amdgcn_mfma_f32_16x16x32_bf16(Bq[kk], a, aE, 0, 0, 0);
      }
      if (cIdx < 8) {
        f32x4 b1a = *(const f32x4*)(b1_el + wv * 32 + kg * 4);
        *(f32x4*)(s_embc + cIdx * 256 + wv * 32 + kg * 4) = aE + b1a;
      }
      __builtin_amdgcn_sched_barrier(0);
#pragma unroll
      for (int kk = 0; kk < 4; ++kk)
        Bq[kk] = *(const bf16x8*)(wpk + (size_t)((kk * 4 + kg) * 256 + col + 16) * 8);
      aE = (f32x4){0, 0, 0, 0};
#pragma unroll
      for (int kk = 0; kk < 4; ++kk) {
        bf16x8 a = *(const bf16x8*)(s_emb + cIdx * 128 + ((kk * 4 + kg) ^ cIdx) * 8);
        aE = __builtin_amdgcn_mfma_f32_16x16x32_bf16(Bq[kk], a, aE, 0, 0, 0);
      }
      if (cIdx < 8) {
        f32x4 b1b = *(const f32x4*)(b1_el + wv * 32 + 16 + kg * 4);
        *(f32x4*)(s_embc + cIdx * 256 + wv * 32 + 16 + kg * 4) = aE + b1b;
      }
    }

    // ---- write chunk 0 ----
    {
      uint4 pk;
      pk.x = pk2(la.x, la.y); pk.y = pk2(la.z, la.w);
      pk.z = pk2(lb.x, lb.y); pk.w = pk2(lb.z, lb.w);
      *(uint4*)(s_msg + lr * 128 + ((ch2 ^ (lr & 15)) * 8)) = pk;
    }

    __syncthreads();

    // ---- main: 8 chunks x (2 nt-phases x 2 tiles) ----
#pragma unroll 1
    for (int c = 0; c < 8; ++c) {
      if (c < 7) {
        la = *(const float4*)mptr;
        lb = *(const float4*)(mptr + 4);
        mptr += 31 * 128;
      }
      const unsigned short* mb = s_msg + (c & 1) * 4096;
      const float* ec = s_embc + c * 256;
      float pA0, pA1, pB0, pB1;
      {
        bf16x8 Bq[4];
#pragma unroll
        for (int kk = 0; kk < 4; ++kk)
          Bq[kk] = *(const bf16x8*)(wpk + (size_t)(((kk + 4) * 4 + kg) * 256 + col) * 8);
        f32x4 w2a = *(const f32x4*)(s_w2 + wv * 32 + kg * 4);
#pragma unroll
        for (int tt = 0; tt < 2; ++tt) {
          f32x4 acc = *(const f32x4*)(ec + wv * 32 + kg * 4);
          const unsigned short* mp = mb + (tt * 16 + cIdx) * 128;
#pragma unroll
          for (int kk = 0; kk < 4; ++kk) {
            bf16x8 a = *(const bf16x8*)(mp + ((kk * 4 + kg) ^ cIdx) * 8);
            acc = __builtin_amdgcn_mfma_f32_16x16x32_bf16(Bq[kk], a, acc, 0, 0, 0);
          }
          float p = 0.0f;
#pragma unroll
          for (int r = 0; r < 4; ++r) p += silu_f(acc[r]) * w2a[r];
          if (tt == 0) pA0 = p; else pA1 = p;
        }
        __builtin_amdgcn_sched_barrier(0);
#pragma unroll
        for (int kk = 0; kk < 4; ++kk)
          Bq[kk] = *(const bf16x8*)(wpk + (size_t)(((kk + 4) * 4 + kg) * 256 + col + 16) * 8);
        f32x4 w2b = *(const f32x4*)(s_w2 + wv * 32 + 16 + kg * 4);
#pragma unroll
        for (int tt = 0; tt < 2; ++tt) {
          f32x4 acc = *(const f32x4*)(ec + wv * 32 + 16 + kg * 4);
          const unsigned short* mp = mb + (tt * 16 + cIdx) * 128;
#pragma unroll
          for (int kk = 0; kk < 4; ++kk) {
            bf16x8 a = *(const bf16x8*)(mp + ((kk * 4 + kg) ^ cIdx) * 8);
            acc = __builtin_amdgcn_mfma_f32_16x16x32_bf16(Bq[kk], a, acc, 0, 0, 0);
          }
          float p = 0.0f;
#pragma unroll
          for (int r = 0; r < 4; ++r) p += silu_f(acc[r]) * w2b[r];
          if (tt == 0) pB0 = p; else pB1 = p;
        }
      }
#pragma unroll
      for (int tt = 0; tt < 2; ++tt) {
        float v = (tt == 0) ? (pA0 + pB0) : (pA1 + pB1);
        v += __shfl_xor(v, 16);
        v += __shfl_xor(v, 32);
        if (kg == 0) s_fp[wv][(c * 2 + tt) * 16 + cIdx] = v;
      }
      if (c < 7) {
        uint4 pk;
        pk.x = pk2(la.x, la.y); pk.y = pk2(la.z, la.w);
        pk.z = pk2(lb.x, lb.y); pk.w = pk2(lb.z, lb.w);
        *(uint4*)(s_msg + ((c + 1) & 1) * 4096 + lr * 128 +
                  ((ch2 ^ (lr & 15)) * 8)) = pk;
      }
      __syncthreads();
    }

    // ---- geometry epilogue ----
    if (tid < 248) {
      int p = tid / 31, jj = tid - p * 31;
      int gp = gp0 + p, b = gp >> 5, i = gp & 31;
      int jidx = jj + (jj >= i ? 1 : 0);
      const float* rsb = rs + b * 96;
      float dx = rsb[jidx * 3 + 0] - rsb[i * 3 + 0];
      float dy = rsb[jidx * 3 + 1] - rsb[i * 3 + 1];
      float dz = rsb[jidx * 3 + 2] - rsb[i * 3 + 2];
      float tq = dx * dx + dy * dy + dz * dz;
      int row = p * 32 + jj;
      float f = b2_el[0];
#pragma unroll
      for (int w = 0; w < 8; ++w) f += s_fp[w][row];
      float g = f * __builtin_amdgcn_rcpf(1.0f + tq * sqrtf(tq));
      atomicAdd(&s_ps[p][0], g * dx);
      atomicAdd(&s_ps[p][1], g * dy);
      atomicAdd(&s_ps[p][2], g * dz);
    }
    if (tid < 8) {
      int gp = gp0 + tid, b = gp >> 5, i = gp & 31;
      float x = rs[(b * 32 + i) * 3 + 0];
      float y = rs[(b * 32 + i) * 3 + 1];
      float z = rs[(b * 32 + i) * 3 + 2];
      float dcy = 1.0f;
#pragma unroll
      for (int n = 0; n < 8; ++n) {
        float dx = x - coords[n * 3 + 0];
        float dy = y - coords[n * 3 + 1];
        float dz = z - coords[n * 3 + 2];
        float tq = dx * dx + dy * dy + dz * dz;
        float zc = chg[n];
        dcy *= tanhf(4.0f * tq * zc * zc);
      }
      s_decay[tid] = dcy;
    }
    __syncthreads();
    if (tid < 24) {
      int p = tid / 3, c = tid - p * 3;
      int gp = gp0 + p;
      atomicAdd(&out[gp * 3 + c], OUT_SCALE * s_decay[p] * s_ps[p][c]);
    }
  } else {
    // ======================= NUC PATH =======================
    const int nbid = bid - EL_BLOCKS;
    const int gp0 = nbid * 8;
    const float* msg = msg_nuc;
    const unsigned short* wp = wpk + 8192 * 8;

    if (tid < 32) ((float*)s_ps)[tid] = 0.0f;

    {
      int p = tid >> 4, ch = tid & 15;
      if (tid < 128) {
        const float* src = emb + (gp0 + p) * 128 + ch * 8;
        float4 v0 = *(const float4*)src;
        float4 v1 = *(const float4*)(src + 4);
        uint4 pk;
        pk.x = pk2(v0.x, v0.y); pk.y = pk2(v0.z, v0.w);
        pk.z = pk2(v1.x, v1.y); pk.w = pk2(v1.z, v1.w);
        *(uint4*)(s_emb + p * 128 + (ch ^ p) * 8) = pk;
      } else if (tid < 256) {
        uint4 z = {0u, 0u, 0u, 0u};
        *(uint4*)(s_emb + p * 128 + (ch ^ (p & 15)) * 8) = z;
      }
      if (tid < 256) s_w2[tid] = w2_nuc[tid];
    }

    const int col = wv * 32 + cIdx;

    const float* mptr = msg + (size_t)(gp0 * 8 + lr) * 128 + ch2 * 8;
    float4 la = *(const float4*)mptr;
    float4 lb = *(const float4*)(mptr + 4);
    mptr += 32 * 128;

    __syncthreads();

    // ---- emb contribution, nt-split ----
    {
      bf16x8 Bq[4];
#pragma unroll
      for (int kk = 0; kk < 4; ++kk)
        Bq[kk] = *(const bf16x8*)(wp + (size_t)((kk * 4 + kg) * 256 + col) * 8);
      f32x4 aE = {0, 0, 0, 0};
#pragma unroll
      for (int kk = 0; kk < 4; ++kk) {
        bf16x8 a = *(const bf16x8*)(s_emb + cIdx * 128 + ((kk * 4 + kg) ^ cIdx) * 8);
        aE = __builtin_amdgcn_mfma_f32_16x16x32_bf16(Bq[kk], a, aE, 0, 0, 0);
      }
      if (cIdx < 8) {
        f32x4 b1a = *(const f32x4*)(b1_nuc + wv * 32 + kg * 4);
        *(f32x4*)(s_embc + cIdx * 256 + wv * 32 + kg * 4) = aE + b1a;
      }
      __builtin_amdgcn_sched_barrier(0);
#pragma unroll
      for (int kk = 0; kk < 4; ++kk)
        Bq[kk] = *(const bf16x8*)(wp + (size_t)((kk * 4 + kg) * 256 + col + 16) * 8);
      aE = (f32x4){0, 0, 0, 0};
#pragma unroll
      for (int kk = 0; kk < 4; ++kk) {
        bf16x8 a = *(const bf16x8*)(s_emb + cIdx * 128 + ((kk * 4 + kg) ^ cIdx) * 8);
        aE = __builtin_amdgcn_mfma_f32_16x16x32_bf16(Bq[kk], a, aE, 0, 0, 0);
      }
      if (cIdx < 8) {
        f32x4 b1b = *(const f32x4*)(b1_nuc + wv * 32 + 16 + kg * 4);
        *(f32x4*)(s_embc + cIdx * 256 + wv * 32 + 16 + kg * 4) = aE + b1b;
      }
    }

    {
      uint4 pk;
      pk.x = pk2(la.x, la.y); pk.y = pk2(la.z, la.w);
      pk.z = pk2(lb.x, lb.y); pk.w = pk2(lb.z, lb.w);
      *(uint4*)(s_msg + lr * 128 + ((ch2 ^ (lr & 15)) * 8)) = pk;
    }

    __syncthreads();

#pragma unroll 1
    for (int c = 0; c < 2; ++c) {
      if (c < 1) {
        la = *(const float4*)mptr;
        lb = *(const float4*)(mptr + 4);
      }
      const unsigned short* mb = s_msg + (c & 1) * 4096;
      float pA0, pA1, pB0, pB1;
      {
        bf16x8 Bq[4];
#pragma unroll
        for (int kk = 0; kk < 4; ++kk)
          Bq[kk] = *(const bf16x8*)(wp + (size_t)(((kk + 4) * 4 + kg) * 256 + col) * 8);
        f32x4 w2a = *(const f32x4*)(s_w2 + wv * 32 + kg * 4);
#pragma unroll
        for (int tt = 0; tt < 2; ++tt) {
          int p = 4 * c + 2 * tt + (cIdx >> 3);
          f32x4 acc = *(const f32x4*)(s_embc + p * 256 + wv * 32 + kg * 4);
          const unsigned short* mp = mb + (tt * 16 + cIdx) * 128;
#pragma unroll
          for (int kk = 0; kk < 4; ++kk) {
            bf16x8 a = *(const bf16x8*)(mp + ((kk * 4 + kg) ^ cIdx) * 8);
            acc = __builtin_amdgcn_mfma_f32_16x16x32_bf16(Bq[kk], a, acc, 0, 0, 0);
          }
          float p2 = 0.0f;
#pragma unroll
          for (int r = 0; r < 4; ++r) p2 += silu_f(acc[r]) * w2a[r];
          if (tt == 0) pA0 = p2; else pA1 = p2;
        }
        __builtin_amdgcn_sched_barrier(0);
#pragma unroll
        for (int kk = 0; kk < 4; ++kk)
          Bq[kk] = *(const bf16x8*)(wp + (size_t)(((kk + 4) * 4 + kg) * 256 + col + 16) * 8);
        f32x4 w2b = *(const f32x4*)(s_w2 + wv * 32 + 16 + kg * 4);
#pragma unroll
        for (int tt = 0; tt < 2; ++tt) {
          int p = 4 * c + 2 * tt + (cIdx >> 3);
          f32x4 acc = *(const f32x4*)(s_embc + p * 256 + wv * 32 + 16 + kg * 4);
          const unsigned short* mp = mb + (tt * 16 + cIdx) * 128;
#pragma unroll
          for (int kk = 0; kk < 4; ++kk) {
            bf16x8 a = *(const bf16x8*)(mp + ((kk * 4 + kg) ^ cIdx) * 8);
            acc = __builtin_amdgcn_mfma_f32_16x16x32_bf16(Bq[kk], a, acc, 0, 0, 0);
          }
          float p2 = 0.0f;
#pragma unroll
          for (int r = 0; r < 4; ++r) p2 += silu_f(acc[r]) * w2b[r];
          if (tt == 0) pB0 = p2; else pB1 = p2;
        }
      }
#pragma unroll
      for (int tt = 0; tt < 2; ++tt) {
        float v = (tt == 0) ? (pA0 + pB0) : (pA1 + pB1);
        v += __shfl_xor(v, 16);
        v += __shfl_xor(v, 32);
        if (kg == 0) s_fp[wv][(c * 2 + tt) * 16 + cIdx] = v;
      }
      if (c < 1) {
        uint4 pk;
        pk.x = pk2(la.x, la.y); pk.y = pk2(la.z, la.w);
        pk.z = pk2(lb.x, lb.y); pk.w = pk2(lb.z, lb.w);
        *(uint4*)(s_msg + 4096 + lr * 128 + ((ch2 ^ (lr & 15)) * 8)) = pk;
      }
      __syncthreads();
    }

    if (tid < 64) {
      int p = tid >> 3, n = tid & 7;
      int gp = gp0 + p, b = gp >> 5, i = gp & 31;
      float dx = rs[(b * 32 + i) * 3 + 0] - coords[n * 3 + 0];
      float dy = rs[(b * 32 + i) * 3 + 1] - coords[n * 3 + 1];
      float dz = rs[(b * 32 + i) * 3 + 2] - coords[n * 3 + 2];
      float tq = dx * dx + dy * dy + dz * dz;
      float f = b2_nuc[0];
#pragma unroll
      for (int w = 0; w < 8; ++w) f += s_fp[w][tid];
      float g = f * __builtin_amdgcn_rcpf(1.0f + tq * sqrtf(tq));
      atomicAdd(&s_ps[p][0], g * dx);
      atomicAdd(&s_ps[p][1], g * dy);
      atomicAdd(&s_ps[p][2], g * dz);
    }
    if (tid < 8) {
      int gp = gp0 + tid, b = gp >> 5, i = gp & 31;
      float x = rs[(b * 32 + i) * 3 + 0];
      float y = rs[(b * 32 + i) * 3 + 1];
      float z = rs[(b * 32 + i) * 3 + 2];
      float dcy = 1.0f;
#pragma unroll
      for (int n = 0; n < 8; ++n) {
        float dx = x - coords[n * 3 + 0];
        float dy = y - coords[n * 3 + 1];
        float dz = z - coords[n * 3 + 2];
        float tq = dx * dx + dy * dy + dz * dz;
        float zc = chg[n];
        dcy *= tanhf(4.0f * tq * zc * zc);
      }
      s_decay[tid] = dcy;
    }
    __syncthreads();
    if (tid < 24) {
      int p = tid / 3, c = tid - p * 3;
      int gp = gp0 + p;
      atomicAdd(&out[gp * 3 + c], OUT_SCALE * s_decay[p] * s_ps[p][c]);
    }
  }
}

extern "C" void kernel_launch(void* const* d_in, const int* in_sizes, int n_in,
                              void* d_out, int out_size, void* d_ws, size_t ws_size,
                              hipStream_t stream) {
  const float* rs       = (const float*)d_in[0];
  const float* coords   = (const float*)d_in[1];
  const float* msg_el   = (const float*)d_in[2];
  const float* msg_nuc  = (const float*)d_in[3];
  const float* emb      = (const float*)d_in[4];
  const float* w1_el    = (const float*)d_in[5];
  const float* b1_el    = (const float*)d_in[6];
  const float* w2_el    = (const float*)d_in[7];
  const float* b2_el    = (const float*)d_in[8];
  const float* w1_nuc   = (const float*)d_in[9];
  const float* b1_nuc   = (const float*)d_in[10];
  const float* w2_nuc   = (const float*)d_in[11];
  const float* b2_nuc   = (const float*)d_in[12];
  const float* chg      = (const float*)d_in[13];
  float* out = (float*)d_out;

  unsigned short* wpk = (unsigned short*)d_ws;  // 256 KB used

  hipMemsetAsync(out, 0, (size_t)out_size * sizeof(float), stream);
  prep_w1<<<64, 256, 0, stream>>>(w1_el, w1_nuc, wpk);
  bf_main_kernel<<<EL_BLOCKS + NUC_BLOCKS, 512, 0, stream>>>(
      rs, msg_el, msg_nuc, emb, wpk, b1_el, w2_el, b2_el, b1_nuc, w2_nuc,
      b2_nuc, coords, chg, out);
}

// Round 12
// 157.638 us; speedup vs baseline: 1.1785x; 1.1785x over previous
//
#include <hip/hip_runtime.h>
#include <hip/hip_bf16.h>

#define OUT_SCALE 0.030197383422318501f  // exp(-3.5)

typedef __attribute__((ext_vector_type(8))) short bf16x8;
typedef __attribute__((ext_vector_type(4))) float f32x4;

#define EL_BLOCKS 2048
#define NUC_BLOCKS 2048

__device__ __forceinline__ unsigned pk2(float a, float b) {
  __hip_bfloat162 h = __float22bfloat162_rn(make_float2(a, b));
  unsigned u;
  __builtin_memcpy(&u, &h, 4);
  return u;
}

__device__ __forceinline__ float silu_f(float h) {
  return h * __builtin_amdgcn_rcpf(1.0f + __expf(-h));
}

// ---------------------------------------------------------------------------
// Prep: pack w1_el / w1_nuc into MFMA fragment layout, bf16.
// Fragment (mlp, kk, kg, col) = 8 bf16 of w1[kk*32+kg*8 .. +8)[col].
// ---------------------------------------------------------------------------
__global__ void prep_w1(const float* __restrict__ w1a,
                        const float* __restrict__ w1b,
                        unsigned short* __restrict__ wp) {
  int gid = blockIdx.x * 256 + threadIdx.x;  // 16384 fragments
  const float* w1 = (gid < 8192) ? w1a : w1b;
  int rem = gid & 8191;
  int kk = rem >> 10;
  int kg = (rem >> 8) & 3;
  int col = rem & 255;
  const float* src = w1 + (kk * 32 + kg * 8) * 256 + col;
  uint4 v;
  v.x = pk2(src[0 * 256], src[1 * 256]);
  v.y = pk2(src[2 * 256], src[3 * 256]);
  v.z = pk2(src[4 * 256], src[5 * 256]);
  v.w = pk2(src[6 * 256], src[7 * 256]);
  *(uint4*)(wp + (size_t)gid * 8) = v;
}

// ---------------------------------------------------------------------------
// Fused main kernel, 512 threads = 8 waves, 8 pairs/block, BARRIER-FREE main
// loop: wave wv owns pair gp0+wv. It stages that pair's 32 msg rows into a
// WAVE-PRIVATE 8KB LDS buffer (ds_write -> ds_read within one wave: only
// lgkmcnt, no __syncthreads), then loops 16 hidden-phases, reloading 4 W1
// fragments per phase from the L2-resident packed buffer. Lane (cIdx,kg)
// accumulates row cIdx's layer-2 partial across phases; final kg-reduce is
// 2 shuffles. Barriers: 2 (prologue) + 1 (pre-epilogue). Waves desync ->
// latency hides across waves at any occupancy. launch_bounds(512,4): the
// only proven no-spill config (r8/r9/r11: >=6 waves/EU always spills).
// ---------------------------------------------------------------------------
__global__ __launch_bounds__(512, 4) void bf_main_kernel(
    const float* __restrict__ rs, const float* __restrict__ msg_el,
    const float* __restrict__ msg_nuc, const float* __restrict__ emb,
    const unsigned short* __restrict__ wpk,
    const float* __restrict__ b1_el, const float* __restrict__ w2_el,
    const float* __restrict__ b2_el,
    const float* __restrict__ b1_nuc, const float* __restrict__ w2_nuc,
    const float* __restrict__ b2_nuc,
    const float* __restrict__ coords, const float* __restrict__ chg,
    float* __restrict__ out) {
  __shared__ __align__(16) unsigned short s_emb[16 * 128];      // 4 KB
  __shared__ __align__(16) unsigned short s_msg[8 * 32 * 128];  // 64 KB: 8KB/wave
  __shared__ __align__(16) float s_embc[8 * 256];               // 8 KB
  __shared__ __align__(16) float s_w2[256];                     // 1 KB
  __shared__ float s_fp[256];                                   // 1 KB
  __shared__ float s_ps[8][4];
  __shared__ float s_decay[8];

  const int tid = threadIdx.x;
  const int bid = blockIdx.x;
  const int lane = tid & 63;
  const int wv = tid >> 6;
  const int cIdx = lane & 15, kg = lane >> 4;

  if (bid < EL_BLOCKS) {
    // ======================= EL PATH =======================
    const int gp0 = bid * 8;
    const float* msg = msg_el;

    if (tid < 32) ((float*)s_ps)[tid] = 0.0f;

    // ---- stage emb (8 pairs, swizzled; zero rows 8..15) + w2 table ----
    {
      int p = tid >> 4, ch = tid & 15;
      if (tid < 128) {
        const float* src = emb + (gp0 + p) * 128 + ch * 8;
        float4 v0 = *(const float4*)src;
        float4 v1 = *(const float4*)(src + 4);
        uint4 pk;
        pk.x = pk2(v0.x, v0.y); pk.y = pk2(v0.z, v0.w);
        pk.z = pk2(v1.x, v1.y); pk.w = pk2(v1.z, v1.w);
        *(uint4*)(s_emb + p * 128 + (ch ^ p) * 8) = pk;
      } else if (tid < 256) {
        uint4 z = {0u, 0u, 0u, 0u};
        *(uint4*)(s_emb + p * 128 + (ch ^ (p & 15)) * 8) = z;
      }
      if (tid < 256) s_w2[tid] = w2_el[tid];
    }

    __syncthreads();

    // ---- emb-contribution precompute (+b1), wave wv covers hidden wv*32..+32
    {
      const int col = wv * 32 + cIdx;
      bf16x8 Bf[4][2];
#pragma unroll
      for (int nt = 0; nt < 2; ++nt)
#pragma unroll
        for (int kk = 0; kk < 4; ++kk)
          Bf[kk][nt] = *(const bf16x8*)(
              wpk + (size_t)((kk * 4 + kg) * 256 + col + nt * 16) * 8);
      f32x4 aE0 = {0, 0, 0, 0}, aE1 = {0, 0, 0, 0};
#pragma unroll
      for (int kk = 0; kk < 4; ++kk) {
        bf16x8 a = *(const bf16x8*)(
            s_emb + cIdx * 128 + ((kk * 4 + kg) ^ cIdx) * 8);
        aE0 = __builtin_amdgcn_mfma_f32_16x16x32_bf16(Bf[kk][0], a, aE0, 0, 0, 0);
        aE1 = __builtin_amdgcn_mfma_f32_16x16x32_bf16(Bf[kk][1], a, aE1, 0, 0, 0);
      }
      if (cIdx < 8) {
        f32x4 b1a = *(const f32x4*)(b1_el + wv * 32 + kg * 4);
        f32x4 b1b = *(const f32x4*)(b1_el + wv * 32 + 16 + kg * 4);
        *(f32x4*)(s_embc + cIdx * 256 + wv * 32 + kg * 4) = aE0 + b1a;
        *(f32x4*)(s_embc + cIdx * 256 + wv * 32 + 16 + kg * 4) = aE1 + b1b;
      }
    }

    __syncthreads();

    // ================= barrier-free main: wave owns pair =================
    const int gp = gp0 + wv;
    unsigned short* myms = s_msg + wv * 4096;  // 32 rows x 128 shorts

    // stage 32 rows (row 31 = clamped duplicate, never read by epilogue)
#pragma unroll 4
    for (int u = 0; u < 8; ++u) {
      int id = u * 64 + lane;
      int row = id >> 4, ch = id & 15;
      int jc = row < 31 ? row : 30;
      const float* s = msg + (size_t)(gp * 31 + jc) * 128 + ch * 8;
      float4 a = *(const float4*)s;
      float4 b = *(const float4*)(s + 4);
      uint4 pk;
      pk.x = pk2(a.x, a.y); pk.y = pk2(a.z, a.w);
      pk.z = pk2(b.x, b.y); pk.w = pk2(b.z, b.w);
      *(uint4*)(myms + row * 128 + ((ch ^ (row & 15)) * 8)) = pk;
    }

    const unsigned short* mp0 = myms + cIdx * 128;
    const unsigned short* mp1 = myms + (16 + cIdx) * 128;
    const float* ec = s_embc + wv * 256;
    float part0 = 0.0f, part1 = 0.0f;
#pragma unroll 2
    for (int ph = 0; ph < 16; ++ph) {
      bf16x8 Bq[4];
#pragma unroll
      for (int kk = 0; kk < 4; ++kk)
        Bq[kk] = *(const bf16x8*)(
            wpk + (size_t)(((kk + 4) * 4 + kg) * 256 + ph * 16 + cIdx) * 8);
      f32x4 init = *(const f32x4*)(ec + ph * 16 + kg * 4);
      f32x4 acc0 = init, acc1 = init;
#pragma unroll
      for (int kk = 0; kk < 4; ++kk) {
        int sw = ((kk * 4 + kg) ^ cIdx) * 8;
        bf16x8 a0 = *(const bf16x8*)(mp0 + sw);
        bf16x8 a1 = *(const bf16x8*)(mp1 + sw);
        acc0 = __builtin_amdgcn_mfma_f32_16x16x32_bf16(Bq[kk], a0, acc0, 0, 0, 0);
        acc1 = __builtin_amdgcn_mfma_f32_16x16x32_bf16(Bq[kk], a1, acc1, 0, 0, 0);
      }
      f32x4 w2v = *(const f32x4*)(s_w2 + ph * 16 + kg * 4);
#pragma unroll
      for (int r = 0; r < 4; ++r) {
        part0 += silu_f(acc0[r]) * w2v[r];
        part1 += silu_f(acc1[r]) * w2v[r];
      }
    }
    part0 += __shfl_xor(part0, 16);
    part0 += __shfl_xor(part0, 32);
    part1 += __shfl_xor(part1, 16);
    part1 += __shfl_xor(part1, 32);
    if (kg == 0) {
      s_fp[wv * 32 + cIdx] = part0;
      s_fp[wv * 32 + 16 + cIdx] = part1;
    }

    __syncthreads();

    // ---- geometry epilogue ----
    if (tid < 248) {
      int p = tid / 31, jj = tid - p * 31;
      int gpx = gp0 + p, b = gpx >> 5, i = gpx & 31;
      int jidx = jj + (jj >= i ? 1 : 0);
      const float* rsb = rs + b * 96;
      float dx = rsb[jidx * 3 + 0] - rsb[i * 3 + 0];
      float dy = rsb[jidx * 3 + 1] - rsb[i * 3 + 1];
      float dz = rsb[jidx * 3 + 2] - rsb[i * 3 + 2];
      float tq = dx * dx + dy * dy + dz * dz;
      float f = s_fp[p * 32 + jj] + b2_el[0];
      float g = f * __builtin_amdgcn_rcpf(1.0f + tq * sqrtf(tq));
      atomicAdd(&s_ps[p][0], g * dx);
      atomicAdd(&s_ps[p][1], g * dy);
      atomicAdd(&s_ps[p][2], g * dz);
    }
    if (tid < 8) {
      int gpx = gp0 + tid, b = gpx >> 5, i = gpx & 31;
      float x = rs[(b * 32 + i) * 3 + 0];
      float y = rs[(b * 32 + i) * 3 + 1];
      float z = rs[(b * 32 + i) * 3 + 2];
      float dcy = 1.0f;
#pragma unroll
      for (int n = 0; n < 8; ++n) {
        float dx = x - coords[n * 3 + 0];
        float dy = y - coords[n * 3 + 1];
        float dz = z - coords[n * 3 + 2];
        float tq = dx * dx + dy * dy + dz * dz;
        float zc = chg[n];
        dcy *= tanhf(4.0f * tq * zc * zc);
      }
      s_decay[tid] = dcy;
    }
    __syncthreads();
    if (tid < 24) {
      int p = tid / 3, c = tid - p * 3;
      int gpx = gp0 + p;
      atomicAdd(&out[gpx * 3 + c], OUT_SCALE * s_decay[p] * s_ps[p][c]);
    }
  } else {
    // ======================= NUC PATH =======================
    const int nbid = bid - EL_BLOCKS;
    const int gp0 = nbid * 8;
    const float* msg = msg_nuc;
    const unsigned short* wp = wpk + 8192 * 8;

    if (tid < 32) ((float*)s_ps)[tid] = 0.0f;

    {
      int p = tid >> 4, ch = tid & 15;
      if (tid < 128) {
        const float* src = emb + (gp0 + p) * 128 + ch * 8;
        float4 v0 = *(const float4*)src;
        float4 v1 = *(const float4*)(src + 4);
        uint4 pk;
        pk.x = pk2(v0.x, v0.y); pk.y = pk2(v0.z, v0.w);
        pk.z = pk2(v1.x, v1.y); pk.w = pk2(v1.z, v1.w);
        *(uint4*)(s_emb + p * 128 + (ch ^ p) * 8) = pk;
      } else if (tid < 256) {
        uint4 z = {0u, 0u, 0u, 0u};
        *(uint4*)(s_emb + p * 128 + (ch ^ (p & 15)) * 8) = z;
      }
      if (tid < 256) s_w2[tid] = w2_nuc[tid];
    }

    __syncthreads();

    {
      const int col = wv * 32 + cIdx;
      bf16x8 Bf[4][2];
#pragma unroll
      for (int nt = 0; nt < 2; ++nt)
#pragma unroll
        for (int kk = 0; kk < 4; ++kk)
          Bf[kk][nt] = *(const bf16x8*)(
              wp + (size_t)((kk * 4 + kg) * 256 + col + nt * 16) * 8);
      f32x4 aE0 = {0, 0, 0, 0}, aE1 = {0, 0, 0, 0};
#pragma unroll
      for (int kk = 0; kk < 4; ++kk) {
        bf16x8 a = *(const bf16x8*)(
            s_emb + cIdx * 128 + ((kk * 4 + kg) ^ cIdx) * 8);
        aE0 = __builtin_amdgcn_mfma_f32_16x16x32_bf16(Bf[kk][0], a, aE0, 0, 0, 0);
        aE1 = __builtin_amdgcn_mfma_f32_16x16x32_bf16(Bf[kk][1], a, aE1, 0, 0, 0);
      }
      if (cIdx < 8) {
        f32x4 b1a = *(const f32x4*)(b1_nuc + wv * 32 + kg * 4);
        f32x4 b1b = *(const f32x4*)(b1_nuc + wv * 32 + 16 + kg * 4);
        *(f32x4*)(s_embc + cIdx * 256 + wv * 32 + kg * 4) = aE0 + b1a;
        *(f32x4*)(s_embc + cIdx * 256 + wv * 32 + 16 + kg * 4) = aE1 + b1b;
      }
    }

    __syncthreads();

    // ---- barrier-free main: wave owns pair (8 rows; cols 8-15 zeroed) ----
    unsigned short* myms = s_msg + wv * 4096;
    // zero rows 8..15
#pragma unroll
    for (int u = 0; u < 2; ++u) {
      int id = u * 64 + lane;
      int row = 8 + (id >> 4), ch = id & 15;
      uint4 z = {0u, 0u, 0u, 0u};
      *(uint4*)(myms + row * 128 + ch * 8) = z;
    }
    // stage 8 rows
#pragma unroll
    for (int u = 0; u < 2; ++u) {
      int id = u * 64 + lane;
      int row = id >> 4, ch = id & 15;
      const float* s = msg + (size_t)((gp0 + wv) * 8 + row) * 128 + ch * 8;
      float4 a = *(const float4*)s;
      float4 b = *(const float4*)(s + 4);
      uint4 pk;
      pk.x = pk2(a.x, a.y); pk.y = pk2(a.z, a.w);
      pk.z = pk2(b.x, b.y); pk.w = pk2(b.z, b.w);
      *(uint4*)(myms + row * 128 + ((ch ^ row) * 8)) = pk;
    }

    const unsigned short* mp0 = myms + cIdx * 128;
    const float* ec = s_embc + wv * 256;
    float part0 = 0.0f;
#pragma unroll 2
    for (int ph = 0; ph < 16; ++ph) {
      bf16x8 Bq[4];
#pragma unroll
      for (int kk = 0; kk < 4; ++kk)
        Bq[kk] = *(const bf16x8*)(
            wp + (size_t)(((kk + 4) * 4 + kg) * 256 + ph * 16 + cIdx) * 8);
      f32x4 acc0 = *(const f32x4*)(ec + ph * 16 + kg * 4);
#pragma unroll
      for (int kk = 0; kk < 4; ++kk) {
        bf16x8 a0 = *(const bf16x8*)(mp0 + ((kk * 4 + kg) ^ cIdx) * 8);
        acc0 = __builtin_amdgcn_mfma_f32_16x16x32_bf16(Bq[kk], a0, acc0, 0, 0, 0);
      }
      f32x4 w2v = *(const f32x4*)(s_w2 + ph * 16 + kg * 4);
#pragma unroll
      for (int r = 0; r < 4; ++r) part0 += silu_f(acc0[r]) * w2v[r];
    }
    part0 += __shfl_xor(part0, 16);
    part0 += __shfl_xor(part0, 32);
    if (kg == 0 && cIdx < 8) s_fp[wv * 8 + cIdx] = part0;

    __syncthreads();

    if (tid < 64) {
      int p = tid >> 3, n = tid & 7;
      int gpx = gp0 + p, b = gpx >> 5, i = gpx & 31;
      float dx = rs[(b * 32 + i) * 3 + 0] - coords[n * 3 + 0];
      float dy = rs[(b * 32 + i) * 3 + 1] - coords[n * 3 + 1];
      float dz = rs[(b * 32 + i) * 3 + 2] - coords[n * 3 + 2];
      float tq = dx * dx + dy * dy + dz * dz;
      float f = s_fp[tid] + b2_nuc[0];
      float g = f * __builtin_amdgcn_rcpf(1.0f + tq * sqrtf(tq));
      atomicAdd(&s_ps[p][0], g * dx);
      atomicAdd(&s_ps[p][1], g * dy);
      atomicAdd(&s_ps[p][2], g * dz);
    }
    if (tid < 8) {
      int gpx = gp0 + tid, b = gpx >> 5, i = gpx & 31;
      float x = rs[(b * 32 + i) * 3 + 0];
      float y = rs[(b * 32 + i) * 3 + 1];
      float z = rs[(b * 32 + i) * 3 + 2];
      float dcy = 1.0f;
#pragma unroll
      for (int n = 0; n < 8; ++n) {
        float dx = x - coords[n * 3 + 0];
        float dy = y - coords[n * 3 + 1];
        float dz = z - coords[n * 3 + 2];
        float tq = dx * dx + dy * dy + dz * dz;
        float zc = chg[n];
        dcy *= tanhf(4.0f * tq * zc * zc);
      }
      s_decay[tid] = dcy;
    }
    __syncthreads();
    if (tid < 24) {
      int p = tid / 3, c = tid - p * 3;
      int gpx = gp0 + p;
      atomicAdd(&out[gpx * 3 + c], OUT_SCALE * s_decay[p] * s_ps[p][c]);
    }
  }
}

extern "C" void kernel_launch(void* const* d_in, const int* in_sizes, int n_in,
                              void* d_out, int out_size, void* d_ws, size_t ws_size,
                              hipStream_t stream) {
  const float* rs       = (const float*)d_in[0];
  const float* coords   = (const float*)d_in[1];
  const float* msg_el   = (const float*)d_in[2];
  const float* msg_nuc  = (const float*)d_in[3];
  const float* emb      = (const float*)d_in[4];
  const float* w1_el    = (const float*)d_in[5];
  const float* b1_el    = (const float*)d_in[6];
  const float* w2_el    = (const float*)d_in[7];
  const float* b2_el    = (const float*)d_in[8];
  const float* w1_nuc   = (const float*)d_in[9];
  const float* b1_nuc   = (const float*)d_in[10];
  const float* w2_nuc   = (const float*)d_in[11];
  const float* b2_nuc   = (const float*)d_in[12];
  const float* chg      = (const float*)d_in[13];
  float* out = (float*)d_out;

  unsigned short* wpk = (unsigned short*)d_ws;  // 256 KB used

  hipMemsetAsync(out, 0, (size_t)out_size * sizeof(float), stream);
  prep_w1<<<64, 256, 0, stream>>>(w1_el, w1_nuc, wpk);
  bf_main_kernel<<<EL_BLOCKS + NUC_BLOCKS, 512, 0, stream>>>(
      rs, msg_el, msg_nuc, emb, wpk, b1_el, w2_el, b2_el, b1_nuc, w2_nuc,
      b2_nuc, coords, chg, out);
}

// Round 13
// 114.764 us; speedup vs baseline: 1.6187x; 1.3736x over previous
//
#include <hip/hip_runtime.h>
#include <hip/hip_bf16.h>

#define OUT_SCALE 0.030197383422318501f  // exp(-3.5)

typedef __attribute__((ext_vector_type(8))) short bf16x8;
typedef __attribute__((ext_vector_type(4))) float f32x4;

#define EL_BLOCKS 1024
#define NUC_BLOCKS 1024

__device__ __forceinline__ unsigned pk2(float a, float b) {
  __hip_bfloat162 h = __float22bfloat162_rn(make_float2(a, b));
  unsigned u;
  __builtin_memcpy(&u, &h, 4);
  return u;
}

__device__ __forceinline__ float silu_f(float h) {
  return h * __builtin_amdgcn_rcpf(1.0f + __expf(-h));
}

// ---------------------------------------------------------------------------
// Prep: pack w1_el / w1_nuc into MFMA fragment layout, bf16.
// Fragment (mlp, kk, kg, col) = 8 bf16 of w1[kk*32+kg*8 .. +8)[col].
// ---------------------------------------------------------------------------
__global__ void prep_w1(const float* __restrict__ w1a,
                        const float* __restrict__ w1b,
                        unsigned short* __restrict__ wp) {
  int gid = blockIdx.x * 256 + threadIdx.x;  // 16384 fragments
  const float* w1 = (gid < 8192) ? w1a : w1b;
  int rem = gid & 8191;
  int kk = rem >> 10;
  int kg = (rem >> 8) & 3;
  int col = rem & 255;
  const float* src = w1 + (kk * 32 + kg * 8) * 256 + col;
  uint4 v;
  v.x = pk2(src[0 * 256], src[1 * 256]);
  v.y = pk2(src[2 * 256], src[3 * 256]);
  v.z = pk2(src[4 * 256], src[5 * 256]);
  v.w = pk2(src[6 * 256], src[7 * 256]);
  *(uint4*)(wp + (size_t)gid * 8) = v;
}

// ---------------------------------------------------------------------------
// Fused main kernel, 512 threads = 8 waves x 32 hidden-cols, 16 pairs/block
// for BOTH paths (r13: el went 8->16 pairs to halve prologue count; per-tile
// code identical to the proven r7 kernel).
// el: 16 pairs, 512 padded rows = 8 chunks of 64 (2 pairs/chunk).
// nuc: 16 pairs, 128 rows = 2 chunks of 64.
// Phase 1: emb contribution (+b1) once per pair -> s_embc[16][256] (all 16
// MFMA columns real now). Main: double-buffered 64-row chunks, issue-early/
// write-late, one barrier per chunk; 8 msg MFMAs + acc-init ds_read per tile.
// launch_bounds(512,4): the only no-spill config (r8/r9/r11: >=6 spills).
// ---------------------------------------------------------------------------
__global__ __launch_bounds__(512, 4) void bf_main_kernel(
    const float* __restrict__ rs, const float* __restrict__ msg_el,
    const float* __restrict__ msg_nuc, const float* __restrict__ emb,
    const unsigned short* __restrict__ wpk,
    const float* __restrict__ b1_el, const float* __restrict__ w2_el,
    const float* __restrict__ b2_el,
    const float* __restrict__ b1_nuc, const float* __restrict__ w2_nuc,
    const float* __restrict__ b2_nuc,
    const float* __restrict__ coords, const float* __restrict__ chg,
    float* __restrict__ out) {
  __shared__ __align__(16) unsigned short s_emb[16 * 128];      // 4 KB
  __shared__ __align__(16) unsigned short s_msg[2 * 64 * 128];  // 32 KB
  __shared__ __align__(16) float s_embc[16 * 256];              // 16 KB
  __shared__ float s_fp[8][512];                                // 16 KB
  __shared__ float s_ps[16][4];
  __shared__ float s_decay[16];

  const int tid = threadIdx.x;
  const int bid = blockIdx.x;
  const int lane = tid & 63;
  const int wv = tid >> 6;
  const int cIdx = lane & 15, kg = lane >> 4;

  if (bid < EL_BLOCKS) {
    // ======================= EL PATH =======================
    const int gp0 = bid * 16;
    const float* msg = msg_el;

    if (tid < 64) ((float*)s_ps)[tid] = 0.0f;

    // ---- stage emb (16 pairs, XOR-swizzled chunks) ----
    if (tid < 256) {
      int p = tid >> 4, ch = tid & 15;
      const float* src = emb + (gp0 + p) * 128 + ch * 8;
      float4 v0 = *(const float4*)src;
      float4 v1 = *(const float4*)(src + 4);
      uint4 pk;
      pk.x = pk2(v0.x, v0.y); pk.y = pk2(v0.z, v0.w);
      pk.z = pk2(v1.x, v1.y); pk.w = pk2(v1.z, v1.w);
      *(uint4*)(s_emb + p * 128 + (ch ^ p) * 8) = pk;
    }

    // ---- W1 emb-half fragments + b1/w2 ----
    bf16x8 Bf[4][2];
    float b1v[2][4], w2v[2][4];
    const int col = wv * 32 + cIdx;
#pragma unroll
    for (int nt = 0; nt < 2; ++nt) {
#pragma unroll
      for (int reg = 0; reg < 4; ++reg) {
        int h = wv * 32 + nt * 16 + kg * 4 + reg;
        b1v[nt][reg] = b1_el[h];
        w2v[nt][reg] = w2_el[h];
      }
#pragma unroll
      for (int kk = 0; kk < 4; ++kk)
        Bf[kk][nt] = *(const bf16x8*)(
            wpk + (size_t)((kk * 4 + kg) * 256 + col + nt * 16) * 8);
    }

    // ---- issue chunk-0 loads (64 rows = pairs 0,1) ----
    float4 la[2], lb[2];
#pragma unroll
    for (int u = 0; u < 2; ++u) {
      int id = u * 512 + tid;
      int lrw = id >> 4, ch = id & 15;
      int p = lrw >> 5, j = lrw & 31;
      int jc = j < 31 ? j : 30;
      const float* s = msg + (size_t)((gp0 + p) * 31 + jc) * 128 + ch * 8;
      la[u] = *(const float4*)s;
      lb[u] = *(const float4*)(s + 4);
    }

    __syncthreads();

    // ---- phase 1: emb contribution per pair (8 MFMAs, 16 real cols) ----
    {
      f32x4 aE0 = {b1v[0][0], b1v[0][1], b1v[0][2], b1v[0][3]};
      f32x4 aE1 = {b1v[1][0], b1v[1][1], b1v[1][2], b1v[1][3]};
#pragma unroll
      for (int kk = 0; kk < 4; ++kk) {
        bf16x8 a = *(const bf16x8*)(
            s_emb + cIdx * 128 + ((kk * 4 + kg) ^ cIdx) * 8);
        aE0 = __builtin_amdgcn_mfma_f32_16x16x32_bf16(Bf[kk][0], a, aE0, 0, 0, 0);
        aE1 = __builtin_amdgcn_mfma_f32_16x16x32_bf16(Bf[kk][1], a, aE1, 0, 0, 0);
      }
      *(f32x4*)(s_embc + cIdx * 256 + wv * 32 + kg * 4) = aE0;
      *(f32x4*)(s_embc + cIdx * 256 + wv * 32 + 16 + kg * 4) = aE1;
    }

    // ---- reload Bf with msg-half fragments ----
#pragma unroll
    for (int nt = 0; nt < 2; ++nt)
#pragma unroll
      for (int kk = 0; kk < 4; ++kk)
        Bf[kk][nt] = *(const bf16x8*)(
            wpk + (size_t)(((kk + 4) * 4 + kg) * 256 + col + nt * 16) * 8);

    // ---- write chunk 0 ----
#pragma unroll
    for (int u = 0; u < 2; ++u) {
      int id = u * 512 + tid;
      int lrw = id >> 4, ch = id & 15;
      uint4 pk;
      pk.x = pk2(la[u].x, la[u].y); pk.y = pk2(la[u].z, la[u].w);
      pk.z = pk2(lb[u].x, lb[u].y); pk.w = pk2(lb[u].z, lb[u].w);
      *(uint4*)(s_msg + lrw * 128 + ((ch ^ (lrw & 15)) * 8)) = pk;
    }

    __syncthreads();

    // ---- main: 8 chunks x 4 tiles, double-buffered ----
#pragma unroll 1
    for (int c = 0; c < 8; ++c) {
      if (c < 7) {
#pragma unroll
        for (int u = 0; u < 2; ++u) {
          int id = u * 512 + tid;
          int lrw = id >> 4, ch = id & 15;
          int p = ((c + 1) << 1) + (lrw >> 5);
          int j = lrw & 31;
          int jc = j < 31 ? j : 30;
          const float* s = msg + (size_t)((gp0 + p) * 31 + jc) * 128 + ch * 8;
          la[u] = *(const float4*)s;
          lb[u] = *(const float4*)(s + 4);
        }
      }
      const unsigned short* mb = s_msg + (c & 1) * 8192;
#pragma unroll
      for (int tt = 0; tt < 4; ++tt) {
        int p = (c << 1) + (tt >> 1);
        const float* ec = s_embc + p * 256;
        f32x4 acc0 = *(const f32x4*)(ec + wv * 32 + kg * 4);
        f32x4 acc1 = *(const f32x4*)(ec + wv * 32 + 16 + kg * 4);
        const unsigned short* mp = mb + (tt * 16 + cIdx) * 128;
#pragma unroll
        for (int kk = 0; kk < 4; ++kk) {
          bf16x8 a = *(const bf16x8*)(mp + ((kk * 4 + kg) ^ cIdx) * 8);
          acc0 = __builtin_amdgcn_mfma_f32_16x16x32_bf16(Bf[kk][0], a, acc0, 0, 0, 0);
          acc1 = __builtin_amdgcn_mfma_f32_16x16x32_bf16(Bf[kk][1], a, acc1, 0, 0, 0);
        }
        float p0 = 0.0f, p1 = 0.0f;
#pragma unroll
        for (int reg = 0; reg < 4; ++reg) {
          p0 += silu_f(acc0[reg]) * w2v[0][reg];
          p1 += silu_f(acc1[reg]) * w2v[1][reg];
        }
        float v = p0 + p1;
        v += __shfl_xor(v, 16);
        v += __shfl_xor(v, 32);
        if (kg == 0) s_fp[wv][c * 64 + tt * 16 + cIdx] = v;
      }
      if (c < 7) {
#pragma unroll
        for (int u = 0; u < 2; ++u) {
          int id = u * 512 + tid;
          int lrw = id >> 4, ch = id & 15;
          uint4 pk;
          pk.x = pk2(la[u].x, la[u].y); pk.y = pk2(la[u].z, la[u].w);
          pk.z = pk2(lb[u].x, lb[u].y); pk.w = pk2(lb[u].z, lb[u].w);
          *(uint4*)(s_msg + ((c + 1) & 1) * 8192 + lrw * 128 +
                    ((ch ^ (lrw & 15)) * 8)) = pk;
        }
      }
      __syncthreads();
    }

    // ---- geometry epilogue (16 pairs x 31 rows = 496) ----
    if (tid < 496) {
      int p = tid / 31, jj = tid - p * 31;
      int gp = gp0 + p, b = gp >> 5, i = gp & 31;
      int jidx = jj + (jj >= i ? 1 : 0);
      const float* rsb = rs + b * 96;
      float dx = rsb[jidx * 3 + 0] - rsb[i * 3 + 0];
      float dy = rsb[jidx * 3 + 1] - rsb[i * 3 + 1];
      float dz = rsb[jidx * 3 + 2] - rsb[i * 3 + 2];
      float tq = dx * dx + dy * dy + dz * dz;
      int row = p * 32 + jj;
      float f = b2_el[0];
#pragma unroll
      for (int w = 0; w < 8; ++w) f += s_fp[w][row];
      float g = f * __builtin_amdgcn_rcpf(1.0f + tq * sqrtf(tq));
      atomicAdd(&s_ps[p][0], g * dx);
      atomicAdd(&s_ps[p][1], g * dy);
      atomicAdd(&s_ps[p][2], g * dz);
    }
    if (tid < 16) {
      int gp = gp0 + tid, b = gp >> 5, i = gp & 31;
      float x = rs[(b * 32 + i) * 3 + 0];
      float y = rs[(b * 32 + i) * 3 + 1];
      float z = rs[(b * 32 + i) * 3 + 2];
      float dcy = 1.0f;
#pragma unroll
      for (int n = 0; n < 8; ++n) {
        float dx = x - coords[n * 3 + 0];
        float dy = y - coords[n * 3 + 1];
        float dz = z - coords[n * 3 + 2];
        float tq = dx * dx + dy * dy + dz * dz;
        float zc = chg[n];
        dcy *= tanhf(4.0f * tq * zc * zc);
      }
      s_decay[tid] = dcy;
    }
    __syncthreads();
    if (tid < 48) {
      int p = tid / 3, c = tid - p * 3;
      int gp = gp0 + p;
      atomicAdd(&out[gp * 3 + c], OUT_SCALE * s_decay[p] * s_ps[p][c]);
    }
  } else {
    // ======================= NUC PATH =======================
    const int nbid = bid - EL_BLOCKS;
    const int gp0 = nbid * 16;
    const float* msg = msg_nuc;
    const unsigned short* wp = wpk + 8192 * 8;

    if (tid < 64) ((float*)s_ps)[tid] = 0.0f;

    // ---- stage emb (16 pairs) ----
    if (tid < 256) {
      int p = tid >> 4, ch = tid & 15;
      const float* src = emb + (gp0 + p) * 128 + ch * 8;
      float4 v0 = *(const float4*)src;
      float4 v1 = *(const float4*)(src + 4);
      uint4 pk;
      pk.x = pk2(v0.x, v0.y); pk.y = pk2(v0.z, v0.w);
      pk.z = pk2(v1.x, v1.y); pk.w = pk2(v1.z, v1.w);
      *(uint4*)(s_emb + p * 128 + (ch ^ p) * 8) = pk;
    }

    bf16x8 Bf[4][2];
    float b1v[2][4], w2v[2][4];
    const int col = wv * 32 + cIdx;
#pragma unroll
    for (int nt = 0; nt < 2; ++nt) {
#pragma unroll
      for (int reg = 0; reg < 4; ++reg) {
        int h = wv * 32 + nt * 16 + kg * 4 + reg;
        b1v[nt][reg] = b1_nuc[h];
        w2v[nt][reg] = w2_nuc[h];
      }
#pragma unroll
      for (int kk = 0; kk < 4; ++kk)
        Bf[kk][nt] = *(const bf16x8*)(
            wp + (size_t)((kk * 4 + kg) * 256 + col + nt * 16) * 8);
    }

    float4 la[2], lb[2];
#pragma unroll
    for (int u = 0; u < 2; ++u) {
      int id = u * 512 + tid;
      int lrw = id >> 4, ch = id & 15;
      const float* s = msg + (size_t)(gp0 * 8 + lrw) * 128 + ch * 8;
      la[u] = *(const float4*)s;
      lb[u] = *(const float4*)(s + 4);
    }

    __syncthreads();

    // ---- phase 1: emb contribution per pair ----
    {
      f32x4 aE0 = {b1v[0][0], b1v[0][1], b1v[0][2], b1v[0][3]};
      f32x4 aE1 = {b1v[1][0], b1v[1][1], b1v[1][2], b1v[1][3]};
#pragma unroll
      for (int kk = 0; kk < 4; ++kk) {
        bf16x8 a = *(const bf16x8*)(
            s_emb + cIdx * 128 + ((kk * 4 + kg) ^ cIdx) * 8);
        aE0 = __builtin_amdgcn_mfma_f32_16x16x32_bf16(Bf[kk][0], a, aE0, 0, 0, 0);
        aE1 = __builtin_amdgcn_mfma_f32_16x16x32_bf16(Bf[kk][1], a, aE1, 0, 0, 0);
      }
      *(f32x4*)(s_embc + cIdx * 256 + wv * 32 + kg * 4) = aE0;
      *(f32x4*)(s_embc + cIdx * 256 + wv * 32 + 16 + kg * 4) = aE1;
    }

#pragma unroll
    for (int nt = 0; nt < 2; ++nt)
#pragma unroll
      for (int kk = 0; kk < 4; ++kk)
        Bf[kk][nt] = *(const bf16x8*)(
            wp + (size_t)(((kk + 4) * 4 + kg) * 256 + col + nt * 16) * 8);

#pragma unroll
    for (int u = 0; u < 2; ++u) {
      int id = u * 512 + tid;
      int lrw = id >> 4, ch = id & 15;
      uint4 pk;
      pk.x = pk2(la[u].x, la[u].y); pk.y = pk2(la[u].z, la[u].w);
      pk.z = pk2(lb[u].x, lb[u].y); pk.w = pk2(lb[u].z, lb[u].w);
      *(uint4*)(s_msg + lrw * 128 + ((ch ^ (lrw & 15)) * 8)) = pk;
    }

    __syncthreads();

    // ---- main: 2 chunks x 4 tiles ----
#pragma unroll 1
    for (int c = 0; c < 2; ++c) {
      if (c < 1) {
#pragma unroll
        for (int u = 0; u < 2; ++u) {
          int id = u * 512 + tid;
          int lrw = id >> 4, ch = id & 15;
          const float* s = msg + (size_t)(gp0 * 8 + 64 + lrw) * 128 + ch * 8;
          la[u] = *(const float4*)s;
          lb[u] = *(const float4*)(s + 4);
        }
      }
      const unsigned short* mb = s_msg + (c & 1) * 8192;
#pragma unroll
      for (int tt = 0; tt < 4; ++tt) {
        int t = c * 4 + tt;
        int r = t * 16 + cIdx;  // 0..127
        int p = r >> 3;
        const float* ec = s_embc + p * 256;
        f32x4 acc0 = *(const f32x4*)(ec + wv * 32 + kg * 4);
        f32x4 acc1 = *(const f32x4*)(ec + wv * 32 + 16 + kg * 4);
        const unsigned short* mp = mb + (r & 63) * 128;
#pragma unroll
        for (int kk = 0; kk < 4; ++kk) {
          bf16x8 a = *(const bf16x8*)(mp + ((kk * 4 + kg) ^ cIdx) * 8);
          acc0 = __builtin_amdgcn_mfma_f32_16x16x32_bf16(Bf[kk][0], a, acc0, 0, 0, 0);
          acc1 = __builtin_amdgcn_mfma_f32_16x16x32_bf16(Bf[kk][1], a, acc1, 0, 0, 0);
        }
        float p0 = 0.0f, p1 = 0.0f;
#pragma unroll
        for (int reg = 0; reg < 4; ++reg) {
          p0 += silu_f(acc0[reg]) * w2v[0][reg];
          p1 += silu_f(acc1[reg]) * w2v[1][reg];
        }
        float v = p0 + p1;
        v += __shfl_xor(v, 16);
        v += __shfl_xor(v, 32);
        if (kg == 0) s_fp[wv][t * 16 + cIdx] = v;
      }
      if (c < 1) {
#pragma unroll
        for (int u = 0; u < 2; ++u) {
          int id = u * 512 + tid;
          int lrw = id >> 4, ch = id & 15;
          uint4 pk;
          pk.x = pk2(la[u].x, la[u].y); pk.y = pk2(la[u].z, la[u].w);
          pk.z = pk2(lb[u].x, lb[u].y); pk.w = pk2(lb[u].z, lb[u].w);
          *(uint4*)(s_msg + 8192 + lrw * 128 + ((ch ^ (lrw & 15)) * 8)) = pk;
        }
      }
      __syncthreads();
    }

    if (tid < 128) {
      int p = tid >> 3, n = tid & 7;
      int gp = gp0 + p, b = gp >> 5, i = gp & 31;
      float dx = rs[(b * 32 + i) * 3 + 0] - coords[n * 3 + 0];
      float dy = rs[(b * 32 + i) * 3 + 1] - coords[n * 3 + 1];
      float dz = rs[(b * 32 + i) * 3 + 2] - coords[n * 3 + 2];
      float tq = dx * dx + dy * dy + dz * dz;
      float f = b2_nuc[0];
#pragma unroll
      for (int w = 0; w < 8; ++w) f += s_fp[w][tid];
      float g = f * __builtin_amdgcn_rcpf(1.0f + tq * sqrtf(tq));
      atomicAdd(&s_ps[p][0], g * dx);
      atomicAdd(&s_ps[p][1], g * dy);
      atomicAdd(&s_ps[p][2], g * dz);
    }
    if (tid < 16) {
      int gp = gp0 + tid, b = gp >> 5, i = gp & 31;
      float x = rs[(b * 32 + i) * 3 + 0];
      float y = rs[(b * 32 + i) * 3 + 1];
      float z = rs[(b * 32 + i) * 3 + 2];
      float dcy = 1.0f;
#pragma unroll
      for (int n = 0; n < 8; ++n) {
        float dx = x - coords[n * 3 + 0];
        float dy = y - coords[n * 3 + 1];
        float dz = z - coords[n * 3 + 2];
        float tq = dx * dx + dy * dy + dz * dz;
        float zc = chg[n];
        dcy *= tanhf(4.0f * tq * zc * zc);
      }
      s_decay[tid] = dcy;
    }
    __syncthreads();
    if (tid < 48) {
      int p = tid / 3, c = tid - p * 3;
      int gp = gp0 + p;
      atomicAdd(&out[gp * 3 + c], OUT_SCALE * s_decay[p] * s_ps[p][c]);
    }
  }
}

extern "C" void kernel_launch(void* const* d_in, const int* in_sizes, int n_in,
                              void* d_out, int out_size, void* d_ws, size_t ws_size,
                              hipStream_t stream) {
  const float* rs       = (const float*)d_in[0];
  const float* coords   = (const float*)d_in[1];
  const float* msg_el   = (const float*)d_in[2];
  const float* msg_nuc  = (const float*)d_in[3];
  const float* emb      = (const float*)d_in[4];
  const float* w1_el    = (const float*)d_in[5];
  const float* b1_el    = (const float*)d_in[6];
  const float* w2_el    = (const float*)d_in[7];
  const float* b2_el    = (const float*)d_in[8];
  const float* w1_nuc   = (const float*)d_in[9];
  const float* b1_nuc   = (const float*)d_in[10];
  const float* w2_nuc   = (const float*)d_in[11];
  const float* b2_nuc   = (const float*)d_in[12];
  const float* chg      = (const float*)d_in[13];
  float* out = (float*)d_out;

  unsigned short* wpk = (unsigned short*)d_ws;  // 256 KB used

  hipMemsetAsync(out, 0, (size_t)out_size * sizeof(float), stream);
  prep_w1<<<64, 256, 0, stream>>>(w1_el, w1_nuc, wpk);
  bf_main_kernel<<<EL_BLOCKS + NUC_BLOCKS, 512, 0, stream>>>(
      rs, msg_el, msg_nuc, emb, wpk, b1_el, w2_el, b2_el, b1_nuc, w2_nuc,
      b2_nuc, coords, chg, out);
}